// Round 15
// baseline (190.524 us; speedup 1.0000x reference)
//
#include <hip/hip_runtime.h>
#include <hip/hip_bf16.h>

#define BATCH 16
#define SEQ   2048
#define DIM   128
#define QBLK  64       // q rows per block (4 waves x 16)
#define KVBLK 64
#define NT    (SEQ / KVBLK)
#define PPAD  72       // lds_p row stride (shorts)
#define L2E   1.4426950408889634f
#define THR   8.0f
#define MSENT -100

typedef __attribute__((ext_vector_type(8))) short bf16x8;
typedef __attribute__((ext_vector_type(4))) float f32x4;
typedef __attribute__((ext_vector_type(4))) int   i32x4;
typedef __attribute__((ext_vector_type(4))) unsigned u32x4;

__device__ __forceinline__ unsigned short f2bf(float f) {
  union { float f; unsigned u; } v; v.f = f;
  return (unsigned short)((v.u + 0x7FFFu + ((v.u >> 16) & 1u)) >> 16);  // RTNE
}
__device__ __forceinline__ unsigned packbf(float a, float b) {
  return ((unsigned)f2bf(b) << 16) | (unsigned)f2bf(a);
}

// ---------------- Pass 1a: K f32 -> bf16 (same layout) ----------------
__global__ __launch_bounds__(256) void cvt_k(const float* __restrict__ K,
                                             short* __restrict__ Kb) {
  const size_t i = ((size_t)blockIdx.x * 256 + threadIdx.x) * 8;
  f32x4 a = __builtin_nontemporal_load((const f32x4*)(K + i));
  f32x4 b = __builtin_nontemporal_load((const f32x4*)(K + i + 4));
  u32x4 o = { packbf(a[0], a[1]), packbf(a[2], a[3]),
              packbf(b[0], b[1]), packbf(b[2], b[3]) };
  *(u32x4*)(Kb + i) = o;
}

// ---------------- Pass 1b: V f32 [b][s][d] -> bf16 Vt [b][d][s] ----------------
__global__ __launch_bounds__(256) void cvt_vt(const float* __restrict__ V,
                                              short* __restrict__ Vt) {
  __shared__ unsigned t32[64][65];
  const int tid = threadIdx.x;
  const int b  = blockIdx.x >> 5;
  const int s0 = (blockIdx.x & 31) * 64;
  #pragma unroll
  for (int it = 0; it < 8; ++it) {
    const int idx = tid + it * 256;
    const int r = idx >> 5, c4 = idx & 31;
    f32x4 x = __builtin_nontemporal_load(
        (const f32x4*)(V + ((size_t)b * SEQ + s0 + r) * DIM + c4 * 4));
    t32[r][c4 * 2]     = packbf(x[0], x[1]);
    t32[r][c4 * 2 + 1] = packbf(x[2], x[3]);
  }
  __syncthreads();
  const int d = tid >> 1, sh = tid & 1;
  unsigned short outv[32];
  #pragma unroll
  for (int j = 0; j < 32; ++j) {
    const unsigned u = t32[sh * 32 + j][d >> 1];
    outv[j] = (d & 1) ? (unsigned short)(u >> 16) : (unsigned short)(u & 0xffff);
  }
  short* op = Vt + ((size_t)b * DIM + d) * SEQ + s0 + sh * 32;
  #pragma unroll
  for (int q = 0; q < 4; ++q) {
    bf16x8 y;
    #pragma unroll
    for (int j = 0; j < 8; ++j) y[j] = (short)outv[q * 8 + j];
    *(bf16x8*)(op + q * 8) = y;
  }
}

// ---------------- async 16B global->LDS ----------------
__device__ __forceinline__ void gload16(const void* g, void* l) {
  __builtin_amdgcn_global_load_lds(
      (const __attribute__((address_space(1))) unsigned*)g,
      (__attribute__((address_space(3))) unsigned*)l, 16, 0, 0);
}

// K tile [64 rows x 256B] into LDS; linear dest, pre-swizzled source (#21).
__device__ __forceinline__ void stage_k(const char* __restrict__ Kb2,
                                        int k0, int w, int l, void* kbuf) {
  #pragma unroll
  for (int it = 0; it < 4; ++it) {
    const int ch = w * 4 + it;
    const int r  = ch * 4 + (l >> 4);
    const int sg = (l & 15) ^ (r & 15);
    gload16(Kb2 + (size_t)(k0 + r) * 256 + sg * 16, (char*)kbuf + ch * 1024);
  }
}

// One pipelined tile: softmax/P/PV of tile T overlapped with QK of tile T+1.
// K rotation (R13-proven): iter T (parity PAR) stages K(T+2)->k[PAR];
// QK(T+1) reads k[PAR^1].  V is NOT LDS-staged (m169): PV(T)'s 16 fragments
// load directly from L2-resident Vt at the tile top (~5000cy slack >> 225cy
// L2 latency), pinned early by the sched_barrier.  Full-drain __syncthreads.
#define TILE_BODY(T, PAR, SA, SB, MA, MB)                                      \
  {                                                                            \
    if ((T) + 2 < NT) stage_k(Kb2, ((T) + 2) * KVBLK, w, l, lds_k[(PAR)]);     \
    /* V(T) fragments direct from L2 */                                        \
    _Pragma("unroll") for (int t8 = 0; t8 < 8; ++t8) {                         \
      const short* vrow = VtS + (size_t)(16 * t8 + lr) * SEQ + (T) * KVBLK;    \
      vr[2 * t8]     = *(const bf16x8*)(vrow + g * 8);                         \
      vr[2 * t8 + 1] = *(const bf16x8*)(vrow + 32 + g * 8);                    \
    }                                                                          \
    if ((T) + 1 < NT) {                                                        \
      _Pragma("unroll") for (int sub = 0; sub < 4; ++sub)                      \
          MB[sub] = __builtin_nontemporal_load(                                \
              (const i32x4*)(Mr + ((T) + 1) * KVBLK + 16 * sub + 4 * g));      \
    }                                                                          \
    __builtin_amdgcn_sched_barrier(0);                                         \
    /* mask apply + online softmax (tile T), lane-local q = lr */              \
    _Pragma("unroll") for (int sub = 0; sub < 4; ++sub)                        \
        _Pragma("unroll") for (int i = 0; i < 4; ++i)                          \
            if (MA[sub][i] == MSENT) SA[sub][i] = -1e30f;                      \
    {                                                                          \
      float tm = -1e30f;                                                       \
      _Pragma("unroll") for (int sub = 0; sub < 4; ++sub)                      \
          _Pragma("unroll") for (int i = 0; i < 4; ++i)                        \
              tm = fmaxf(tm, SA[sub][i]);                                      \
      tm = fmaxf(tm, __shfl_xor(tm, 16));                                      \
      tm = fmaxf(tm, __shfl_xor(tm, 32));                                      \
      if (__any(tm > mrow + THR)) {                                            \
        const float mnew = fmaxf(mrow, tm);                                    \
        const float al = __builtin_amdgcn_exp2f((mrow - mnew) * L2E);          \
        mrow = mnew; lsum *= al;                                               \
        float av[4];                                                           \
        _Pragma("unroll") for (int i = 0; i < 4; ++i)                          \
            av[i] = __shfl(al, 4 * g + i);                                     \
        _Pragma("unroll") for (int t8 = 0; t8 < 8; ++t8)                       \
            _Pragma("unroll") for (int i = 0; i < 4; ++i)                      \
                acc[t8][i] *= av[i];                                           \
      }                                                                        \
    }                                                                          \
    /* QK(T+1) from k[(PAR)^1] — MFMA pipe; overlaps P VALU below */           \
    if ((T) + 1 < NT) {                                                        \
      const char* kb_ = (const char*)lds_k[(PAR) ^ 1];                         \
      _Pragma("unroll") for (int sub = 0; sub < 4; ++sub)                      \
          SB[sub] = (f32x4){0.f, 0.f, 0.f, 0.f};                               \
      __builtin_amdgcn_s_setprio(1);                                           \
      _Pragma("unroll") for (int kk = 0; kk < 4; ++kk) {                       \
        const int cb = (64 * kk + 16 * g) ^ (lr << 4);                         \
        _Pragma("unroll") for (int sub = 0; sub < 4; ++sub) {                  \
          bf16x8 kb = *(const bf16x8*)(kb_ + (sub * 16 + lr) * 256 + cb);      \
          SB[sub] = __builtin_amdgcn_mfma_f32_16x16x32_bf16(kb, qa[kk],        \
                                                            SB[sub], 0, 0, 0); \
        }                                                                      \
      }                                                                        \
      __builtin_amdgcn_s_setprio(0);                                           \
    }                                                                          \
    /* P(T) = exp2 + packbf, LDS roundtrip, PV(T) from vr */                   \
    {                                                                          \
      unsigned* prow = (unsigned*)&lds_p[w][lr * PPAD];                        \
      _Pragma("unroll") for (int sub = 0; sub < 4; ++sub) {                    \
        const float p0 = __builtin_amdgcn_exp2f((SA[sub][0] - mrow) * L2E);    \
        const float p1 = __builtin_amdgcn_exp2f((SA[sub][1] - mrow) * L2E);    \
        const float p2 = __builtin_amdgcn_exp2f((SA[sub][2] - mrow) * L2E);    \
        const float p3 = __builtin_amdgcn_exp2f((SA[sub][3] - mrow) * L2E);    \
        lsum += (p0 + p1) + (p2 + p3);                                         \
        prow[8 * sub + 2 * g]     = packbf(p0, p1);                            \
        prow[8 * sub + 2 * g + 1] = packbf(p2, p3);                            \
      }                                                                        \
      bf16x8 pa0 = *(const bf16x8*)&lds_p[w][lr * PPAD + g * 8];               \
      bf16x8 pa1 = *(const bf16x8*)&lds_p[w][lr * PPAD + 32 + g * 8];          \
      __builtin_amdgcn_s_setprio(1);                                           \
      _Pragma("unroll") for (int t8 = 0; t8 < 8; ++t8) {                       \
        acc[t8] = __builtin_amdgcn_mfma_f32_16x16x32_bf16(pa0, vr[2 * t8],     \
                                                          acc[t8], 0, 0, 0);   \
        acc[t8] = __builtin_amdgcn_mfma_f32_16x16x32_bf16(pa1, vr[2 * t8 + 1], \
                                                          acc[t8], 0, 0, 0);   \
      }                                                                        \
      __builtin_amdgcn_s_setprio(0);                                           \
    }                                                                          \
    if ((T) + 1 < NT) __syncthreads();                                         \
  }

// ---------------- Pass 2: pipelined flash attention (swapped QK^T) -----------
__global__ __launch_bounds__(256, 2) void attn_fwd(
    const short* __restrict__ Kbf, const short* __restrict__ Vt,
    const float* __restrict__ Qg, const int* __restrict__ Mg,
    float* __restrict__ Og) {
  __shared__ short lds_k[2][KVBLK * DIM];   // 2 x 16KB
  __shared__ short lds_p[4][16 * PPAD];     // 9KB   (no lds_v: V direct from L2)

  const int tid = threadIdx.x;
  const int w = tid >> 6, l = tid & 63, g = l >> 4, lr = l & 15;

  const int blk = blockIdx.x;
  const int swz = (blk & 7) * 64 + (blk >> 3);   // XCD-chunked (512 % 8 == 0)
  const int b   = swz >> 5;
  const int q0  = (swz & 31) * QBLK;

  const float scale = 0.08838834764831845f;  // 1/sqrt(128)

  const char*  Kb2 = (const char*)(Kbf + (size_t)b * SEQ * DIM);
  const short* VtS = Vt + (size_t)b * DIM * SEQ;
  const int*   Mr  = Mg + (size_t)b * SEQ * SEQ + (size_t)(q0 + w * 16 + lr) * SEQ;

  // ---- stage K(0), K(1); prefetch mask(0)
  stage_k(Kb2, 0,     w, l, lds_k[0]);
  stage_k(Kb2, KVBLK, w, l, lds_k[1]);
  __builtin_amdgcn_sched_barrier(0);
  i32x4 mA[4], mB[4];
  #pragma unroll
  for (int sub = 0; sub < 4; ++sub)
    mA[sub] = __builtin_nontemporal_load((const i32x4*)(Mr + 16 * sub + 4 * g));

  // ---- Q fragments (q = lr; B operand of swapped QK), pre-scaled
  bf16x8 qa[4];
  {
    const float* qbase = Qg + ((size_t)b * SEQ + (size_t)(q0 + w * 16 + lr)) * DIM + g * 8;
    #pragma unroll
    for (int kk = 0; kk < 4; ++kk) {
      f32x4 x0 = *(const f32x4*)(qbase + kk * 32);
      f32x4 x1 = *(const f32x4*)(qbase + kk * 32 + 4);
      bf16x8 f;
      #pragma unroll
      for (int j = 0; j < 4; ++j) {
        f[j]     = (short)f2bf(x0[j] * scale);
        f[j + 4] = (short)f2bf(x1[j] * scale);
      }
      qa[kk] = f;
    }
  }

  f32x4 acc[8];
  #pragma unroll
  for (int t = 0; t < 8; ++t) acc[t] = (f32x4){0.f, 0.f, 0.f, 0.f};
  float mrow = -1e30f, lsum = 0.f;
  bf16x8 vr[16];

  __syncthreads();   // full drain: K(0),K(1),mask(0),Q all landed

  // ---- prologue QK(0) -> sA
  f32x4 sA[4], sB[4];
  #pragma unroll
  for (int sub = 0; sub < 4; ++sub) sA[sub] = (f32x4){0.f, 0.f, 0.f, 0.f};
  {
    const char* kb_ = (const char*)lds_k[0];
    #pragma unroll
    for (int kk = 0; kk < 4; ++kk) {
      const int cb = (64 * kk + 16 * g) ^ (lr << 4);
      #pragma unroll
      for (int sub = 0; sub < 4; ++sub) {
        bf16x8 kb = *(const bf16x8*)(kb_ + (sub * 16 + lr) * 256 + cb);
        sA[sub] = __builtin_amdgcn_mfma_f32_16x16x32_bf16(kb, qa[kk], sA[sub], 0, 0, 0);
      }
    }
  }
  __syncthreads();   // all waves done reading k[0] before iter 0 overwrites it

  for (int t = 0; t < NT; t += 2) {
    TILE_BODY(t,     0, sA, sB, mA, mB);
    TILE_BODY(t + 1, 1, sB, sA, mB, mA);
  }

  // ---- finalize: full row sum, normalize, store
  lsum += __shfl_xor(lsum, 16);
  lsum += __shfl_xor(lsum, 32);
  const float rden = 1.f / lsum;   // valid for q = lr
  float rdv[4];
  #pragma unroll
  for (int i = 0; i < 4; ++i) rdv[i] = __shfl(rden, 4 * g + i);
  float* ob = Og + ((size_t)b * SEQ + (size_t)(q0 + w * 16)) * DIM;
  #pragma unroll
  for (int t8 = 0; t8 < 8; ++t8)
    #pragma unroll
    for (int i = 0; i < 4; ++i)
      ob[(4 * g + i) * DIM + 16 * t8 + lr] = acc[t8][i] * rdv[i];
}

extern "C" void kernel_launch(void* const* d_in, const int* in_sizes, int n_in,
                              void* d_out, int out_size, void* d_ws, size_t ws_size,
                              hipStream_t stream) {
  (void)in_sizes; (void)n_in; (void)out_size; (void)ws_size;
  const float* Vg = (const float*)d_in[0];
  const float* Kg = (const float*)d_in[1];
  const float* Qg = (const float*)d_in[2];
  const int*   Mg = (const int*)d_in[3];
  float* Og = (float*)d_out;

  short* Kbf = (short*)d_ws;                       // 8 MB
  short* Vt  = Kbf + (size_t)BATCH * SEQ * DIM;    // 8 MB
  cvt_k<<<dim3(BATCH * SEQ * DIM / (8 * 256)), 256, 0, stream>>>(Kg, Kbf);
  cvt_vt<<<dim3(BATCH * (SEQ / 64)), 256, 0, stream>>>(Vg, Vt);
  attn_fwd<<<dim3(BATCH * (SEQ / QBLK)), 256, 0, stream>>>(Kbf, Vt, Qg, Mg, Og);
}

// Round 16
// 106.657 us; speedup vs baseline: 1.7863x; 1.7863x over previous
//
#include <hip/hip_runtime.h>
#include <hip/hip_bf16.h>

#define BATCH 16
#define SEQ   2048
#define DIM   128
#define QBLK  64       // q rows per block (4 waves x 16)
#define KVBLK 64
#define NT    (SEQ / KVBLK)
#define PPAD  72       // lds_p row stride (shorts)
#define L2E   1.4426950408889634f
#define THR   8.0f
#define MSENT -100

typedef __attribute__((ext_vector_type(8))) short bf16x8;
typedef __attribute__((ext_vector_type(4))) float f32x4;
typedef __attribute__((ext_vector_type(4))) int   i32x4;
typedef __attribute__((ext_vector_type(4))) unsigned u32x4;

__device__ __forceinline__ unsigned short f2bf(float f) {
  union { float f; unsigned u; } v; v.f = f;
  return (unsigned short)((v.u + 0x7FFFu + ((v.u >> 16) & 1u)) >> 16);  // RTNE
}
__device__ __forceinline__ unsigned packbf(float a, float b) {
  return ((unsigned)f2bf(b) << 16) | (unsigned)f2bf(a);
}

// ------- Pass 1 (merged): K f32->bf16 copy  +  V f32->bf16 transpose -------
// Blocks [0, NKB): K convert.  Blocks [NKB, NKB+NVB): V transpose.
#define NKB (BATCH * SEQ * DIM / (8 * 256))   // 2048
#define NVB (BATCH * (SEQ / 64))              // 512
__global__ __launch_bounds__(256) void cvt_kv(const float* __restrict__ K,
                                              const float* __restrict__ V,
                                              short* __restrict__ Kb,
                                              short* __restrict__ Vt) {
  __shared__ unsigned t32[64][65];
  if (blockIdx.x < NKB) {
    const size_t i = ((size_t)blockIdx.x * 256 + threadIdx.x) * 8;
    f32x4 a = __builtin_nontemporal_load((const f32x4*)(K + i));
    f32x4 b = __builtin_nontemporal_load((const f32x4*)(K + i + 4));
    u32x4 o = { packbf(a[0], a[1]), packbf(a[2], a[3]),
                packbf(b[0], b[1]), packbf(b[2], b[3]) };
    *(u32x4*)(Kb + i) = o;
    return;
  }
  const int vb = blockIdx.x - NKB;
  const int tid = threadIdx.x;
  const int b  = vb >> 5;
  const int s0 = (vb & 31) * 64;
  #pragma unroll
  for (int it = 0; it < 8; ++it) {
    const int idx = tid + it * 256;
    const int r = idx >> 5, c4 = idx & 31;
    f32x4 x = __builtin_nontemporal_load(
        (const f32x4*)(V + ((size_t)b * SEQ + s0 + r) * DIM + c4 * 4));
    t32[r][c4 * 2]     = packbf(x[0], x[1]);
    t32[r][c4 * 2 + 1] = packbf(x[2], x[3]);
  }
  __syncthreads();
  const int d = tid >> 1, sh = tid & 1;
  unsigned short outv[32];
  #pragma unroll
  for (int j = 0; j < 32; ++j) {
    const unsigned u = t32[sh * 32 + j][d >> 1];
    outv[j] = (d & 1) ? (unsigned short)(u >> 16) : (unsigned short)(u & 0xffff);
  }
  short* op = Vt + ((size_t)b * DIM + d) * SEQ + s0 + sh * 32;
  #pragma unroll
  for (int q = 0; q < 4; ++q) {
    bf16x8 y;
    #pragma unroll
    for (int j = 0; j < 8; ++j) y[j] = (short)outv[q * 8 + j];
    *(bf16x8*)(op + q * 8) = y;
  }
}

// ---------------- async 16B global->LDS ----------------
__device__ __forceinline__ void gload16(const void* g, void* l) {
  __builtin_amdgcn_global_load_lds(
      (const __attribute__((address_space(1))) unsigned*)g,
      (__attribute__((address_space(3))) unsigned*)l, 16, 0, 0);
}

// K tile [64 rows x 256B] into LDS; linear dest, pre-swizzled source (#21).
__device__ __forceinline__ void stage_k(const char* __restrict__ Kb2,
                                        int k0, int w, int l, void* kbuf) {
  #pragma unroll
  for (int it = 0; it < 4; ++it) {
    const int ch = w * 4 + it;
    const int r  = ch * 4 + (l >> 4);
    const int sg = (l & 15) ^ (r & 15);
    gload16(Kb2 + (size_t)(k0 + r) * 256 + sg * 16, (char*)kbuf + ch * 1024);
  }
}
// V tile [64 paired-d rows x 256B] into LDS; same both-sides swizzle scheme.
__device__ __forceinline__ void stage_v(const char* __restrict__ Vtb2,
                                        int k0, int w, int l, void* vbuf) {
  #pragma unroll
  for (int it = 0; it < 4; ++it) {
    const int ch = w * 4 + it;
    const int d2 = ch * 4 + (l >> 4);
    const int Su = (l & 15) ^ (d2 & 15);
    const int d  = 2 * d2 + (Su >> 3);
    const int m  = Su & 7;
    gload16(Vtb2 + (size_t)d * (SEQ * 2) + (size_t)k0 * 2 + m * 16,
            (char*)vbuf + ch * 1024);
  }
}

// One pipelined tile: softmax/P/PV of tile T overlapped with QK of tile T+1.
// K/V rotation (R11/R13-proven): iter T (parity PAR) stages K(T+2)->k[PAR],
// V(T+1)->v[PAR^1]; QK(T+1) reads k[PAR^1]; PV(T) reads v[PAR].
// VMEM ORDER CONTRACT (R6-proven): the 8 stage DMA loads issue FIRST, then
// sched_barrier(0); the 4 mask loads issue mid-tile (strictly younger).
// Tile end: s_waitcnt vmcnt(4) waits exactly the stage loads; mask rides
// across the raw s_barrier.  P-pack via packbf ONLY (cvt_pk asm = poison).
#define TILE_BODY(T, PAR, SA, SB, MA, MB)                                      \
  {                                                                            \
    if ((T) + 2 < NT) stage_k(Kb2, ((T) + 2) * KVBLK, w, l, lds_k[(PAR)]);     \
    if ((T) + 1 < NT) stage_v(Vtb2, ((T) + 1) * KVBLK, w, l, lds_v[(PAR) ^ 1]);\
    __builtin_amdgcn_sched_barrier(0);                                         \
    /* mask apply + online softmax (tile T), lane-local q = lr */              \
    _Pragma("unroll") for (int sub = 0; sub < 4; ++sub)                        \
        _Pragma("unroll") for (int i = 0; i < 4; ++i)                          \
            if (MA[sub][i] == MSENT) SA[sub][i] = -1e30f;                      \
    {                                                                          \
      float tm = -1e30f;                                                       \
      _Pragma("unroll") for (int sub = 0; sub < 4; ++sub)                      \
          _Pragma("unroll") for (int i = 0; i < 4; ++i)                        \
              tm = fmaxf(tm, SA[sub][i]);                                      \
      tm = fmaxf(tm, __shfl_xor(tm, 16));                                      \
      tm = fmaxf(tm, __shfl_xor(tm, 32));                                      \
      if (__any(tm > mrow + THR)) {                                            \
        const float mnew = fmaxf(mrow, tm);                                    \
        const float al = __builtin_amdgcn_exp2f((mrow - mnew) * L2E);          \
        mrow = mnew; lsum *= al;                                               \
        float av[4];                                                           \
        _Pragma("unroll") for (int i = 0; i < 4; ++i)                          \
            av[i] = __shfl(al, 4 * g + i);                                     \
        _Pragma("unroll") for (int t8 = 0; t8 < 8; ++t8)                       \
            _Pragma("unroll") for (int i = 0; i < 4; ++i)                      \
                acc[t8][i] *= av[i];                                           \
      }                                                                        \
    }                                                                          \
    /* mask(T+1) loads: AFTER the sched_barrier -> newest in VMEM queue */     \
    if ((T) + 1 < NT) {                                                        \
      _Pragma("unroll") for (int sub = 0; sub < 4; ++sub)                      \
          MB[sub] = __builtin_nontemporal_load(                                \
              (const i32x4*)(Mr + ((T) + 1) * KVBLK + 16 * sub + 4 * g));      \
    }                                                                          \
    /* QK(T+1) from k[(PAR)^1] — MFMA pipe; overlaps P VALU below */           \
    if ((T) + 1 < NT) {                                                        \
      const char* kb_ = (const char*)lds_k[(PAR) ^ 1];                         \
      _Pragma("unroll") for (int sub = 0; sub < 4; ++sub)                      \
          SB[sub] = (f32x4){0.f, 0.f, 0.f, 0.f};                               \
      __builtin_amdgcn_s_setprio(1);                                           \
      _Pragma("unroll") for (int kk = 0; kk < 4; ++kk) {                       \
        const int cb = (64 * kk + 16 * g) ^ (lr << 4);                         \
        _Pragma("unroll") for (int sub = 0; sub < 4; ++sub) {                  \
          bf16x8 kb = *(const bf16x8*)(kb_ + (sub * 16 + lr) * 256 + cb);      \
          SB[sub] = __builtin_amdgcn_mfma_f32_16x16x32_bf16(kb, qa[kk],        \
                                                            SB[sub], 0, 0, 0); \
        }                                                                      \
      }                                                                        \
      __builtin_amdgcn_s_setprio(0);                                           \
    }                                                                          \
    /* P(T) = exp2 + packbf, LDS roundtrip, PV(T) */                           \
    {                                                                          \
      unsigned* prow = (unsigned*)&lds_p[w][lr * PPAD];                        \
      _Pragma("unroll") for (int sub = 0; sub < 4; ++sub) {                    \
        const float p0 = __builtin_amdgcn_exp2f((SA[sub][0] - mrow) * L2E);    \
        const float p1 = __builtin_amdgcn_exp2f((SA[sub][1] - mrow) * L2E);    \
        const float p2 = __builtin_amdgcn_exp2f((SA[sub][2] - mrow) * L2E);    \
        const float p3 = __builtin_amdgcn_exp2f((SA[sub][3] - mrow) * L2E);    \
        lsum += (p0 + p1) + (p2 + p3);                                         \
        prow[8 * sub + 2 * g]     = packbf(p0, p1);                            \
        prow[8 * sub + 2 * g + 1] = packbf(p2, p3);                            \
      }                                                                        \
      bf16x8 pa0 = *(const bf16x8*)&lds_p[w][lr * PPAD + g * 8];               \
      bf16x8 pa1 = *(const bf16x8*)&lds_p[w][lr * PPAD + 32 + g * 8];          \
      const char* vb_ = (const char*)lds_v[(PAR)];                             \
      __builtin_amdgcn_s_setprio(1);                                           \
      _Pragma("unroll") for (int t8 = 0; t8 < 8; ++t8) {                       \
        const int d2 = 8 * t8 + (lr >> 1);                                     \
        const int S0 = (((lr & 1) * 8 + 0 + g) ^ (d2 & 15)) * 16;              \
        const int S1 = (((lr & 1) * 8 + 4 + g) ^ (d2 & 15)) * 16;              \
        bf16x8 v0 = *(const bf16x8*)(vb_ + d2 * 256 + S0);                     \
        acc[t8] = __builtin_amdgcn_mfma_f32_16x16x32_bf16(pa0, v0, acc[t8],    \
                                                          0, 0, 0);            \
        bf16x8 v1 = *(const bf16x8*)(vb_ + d2 * 256 + S1);                     \
        acc[t8] = __builtin_amdgcn_mfma_f32_16x16x32_bf16(pa1, v1, acc[t8],    \
                                                          0, 0, 0);            \
      }                                                                        \
      __builtin_amdgcn_s_setprio(0);                                           \
    }                                                                          \
    if ((T) + 1 < NT) {                                                        \
      asm volatile("s_waitcnt vmcnt(4)" ::: "memory");                         \
      __builtin_amdgcn_s_barrier();                                            \
      __builtin_amdgcn_sched_barrier(0);                                       \
    }                                                                          \
  }

// ---------------- Pass 2: pipelined flash attention (swapped QK^T) -----------
__global__ __launch_bounds__(256, 2) void attn_fwd(
    const short* __restrict__ Kbf, const short* __restrict__ Vt,
    const float* __restrict__ Qg, const int* __restrict__ Mg,
    float* __restrict__ Og) {
  __shared__ short lds_k[2][KVBLK * DIM];   // 2 x 16KB
  __shared__ short lds_v[2][DIM * KVBLK];   // 2 x 16KB
  __shared__ short lds_p[4][16 * PPAD];     // 9KB

  const int tid = threadIdx.x;
  const int w = tid >> 6, l = tid & 63, g = l >> 4, lr = l & 15;

  const int blk = blockIdx.x;
  const int swz = (blk & 7) * 64 + (blk >> 3);   // XCD-chunked (512 % 8 == 0)
  const int b   = swz >> 5;
  const int q0  = (swz & 31) * QBLK;

  const float scale = 0.08838834764831845f;  // 1/sqrt(128)

  const char* Kb2  = (const char*)(Kbf + (size_t)b * SEQ * DIM);
  const char* Vtb2 = (const char*)(Vt  + (size_t)b * DIM * SEQ);
  const int*  Mr   = Mg + (size_t)b * SEQ * SEQ + (size_t)(q0 + w * 16 + lr) * SEQ;

  // ---- stage K(0), K(1), V(0); prefetch mask(0)
  stage_k(Kb2, 0,     w, l, lds_k[0]);
  stage_k(Kb2, KVBLK, w, l, lds_k[1]);
  stage_v(Vtb2, 0,    w, l, lds_v[0]);
  __builtin_amdgcn_sched_barrier(0);
  i32x4 mA[4], mB[4];
  #pragma unroll
  for (int sub = 0; sub < 4; ++sub)
    mA[sub] = __builtin_nontemporal_load((const i32x4*)(Mr + 16 * sub + 4 * g));

  // ---- Q fragments (q = lr; B operand of swapped QK), pre-scaled
  bf16x8 qa[4];
  {
    const float* qbase = Qg + ((size_t)b * SEQ + (size_t)(q0 + w * 16 + lr)) * DIM + g * 8;
    #pragma unroll
    for (int kk = 0; kk < 4; ++kk) {
      f32x4 x0 = *(const f32x4*)(qbase + kk * 32);
      f32x4 x1 = *(const f32x4*)(qbase + kk * 32 + 4);
      bf16x8 f;
      #pragma unroll
      for (int j = 0; j < 4; ++j) {
        f[j]     = (short)f2bf(x0[j] * scale);
        f[j + 4] = (short)f2bf(x1[j] * scale);
      }
      qa[kk] = f;
    }
  }

  f32x4 acc[8];
  #pragma unroll
  for (int t = 0; t < 8; ++t) acc[t] = (f32x4){0.f, 0.f, 0.f, 0.f};
  float mrow = -1e30f, lsum = 0.f;

  __syncthreads();   // full drain: K(0),K(1),V(0),mask(0),Q all landed

  // ---- prologue QK(0) -> sA
  f32x4 sA[4], sB[4];
  #pragma unroll
  for (int sub = 0; sub < 4; ++sub) sA[sub] = (f32x4){0.f, 0.f, 0.f, 0.f};
  {
    const char* kb_ = (const char*)lds_k[0];
    #pragma unroll
    for (int kk = 0; kk < 4; ++kk) {
      const int cb = (64 * kk + 16 * g) ^ (lr << 4);
      #pragma unroll
      for (int sub = 0; sub < 4; ++sub) {
        bf16x8 kb = *(const bf16x8*)(kb_ + (sub * 16 + lr) * 256 + cb);
        sA[sub] = __builtin_amdgcn_mfma_f32_16x16x32_bf16(kb, qa[kk], sA[sub], 0, 0, 0);
      }
    }
  }
  __syncthreads();   // all waves done reading k[0] before iter 0 overwrites it

  for (int t = 0; t < NT; t += 2) {
    TILE_BODY(t,     0, sA, sB, mA, mB);
    TILE_BODY(t + 1, 1, sB, sA, mB, mA);
  }

  // ---- finalize: full row sum, normalize, store
  lsum += __shfl_xor(lsum, 16);
  lsum += __shfl_xor(lsum, 32);
  const float rden = 1.f / lsum;   // valid for q = lr
  float rdv[4];
  #pragma unroll
  for (int i = 0; i < 4; ++i) rdv[i] = __shfl(rden, 4 * g + i);
  float* ob = Og + ((size_t)b * SEQ + (size_t)(q0 + w * 16)) * DIM;
  #pragma unroll
  for (int t8 = 0; t8 < 8; ++t8)
    #pragma unroll
    for (int i = 0; i < 4; ++i)
      ob[(4 * g + i) * DIM + 16 * t8 + lr] = acc[t8][i] * rdv[i];
}

extern "C" void kernel_launch(void* const* d_in, const int* in_sizes, int n_in,
                              void* d_out, int out_size, void* d_ws, size_t ws_size,
                              hipStream_t stream) {
  (void)in_sizes; (void)n_in; (void)out_size; (void)ws_size;
  const float* Vg = (const float*)d_in[0];
  const float* Kg = (const float*)d_in[1];
  const float* Qg = (const float*)d_in[2];
  const int*   Mg = (const int*)d_in[3];
  float* Og = (float*)d_out;

  short* Kbf = (short*)d_ws;                       // 8 MB
  short* Vt  = Kbf + (size_t)BATCH * SEQ * DIM;    // 8 MB
  cvt_kv<<<dim3(NKB + NVB), 256, 0, stream>>>(Kg, Vg, Kbf, Vt);
  attn_fwd<<<dim3(BATCH * (SEQ / QBLK)), 256, 0, stream>>>(Kbf, Vt, Qg, Mg, Og);
}